// Round 6
// baseline (289.144 us; speedup 1.0000x reference)
//
#include <hip/hip_runtime.h>
#include <math.h>

#define BATCH 64
#define H 80
#define W 80
#define C 80
#define CP4 84
#define TOPK 100
#define THRESH 2.5f
#define NBINS 4096
#define COLLECT_CAP 2048
#define SPLITS 4
#define RPT (H / SPLITS)       // 20 rows per block
#define JT 16                  // owned j-pixels per block
#define JB (W / JT)            // 5 j-tiles
#define NSEG (SPLITS * JB)     // 20 candidate segments per batch
#define SEGCAP 1024
#define BLK 320                // 5 waves; cg inner => contiguous 320B runs per j

// float -> monotonic sortable uint (ascending key == ascending float)
__device__ __forceinline__ unsigned int f2key(float f) {
    unsigned int u = __float_as_uint(f);
    return (u & 0x80000000u) ? ~u : (u | 0x80000000u);
}
__device__ __forceinline__ float key2f(unsigned int k) {
    unsigned int u = (k & 0x80000000u) ? (k & 0x7FFFFFFFu) : ~k;
    return __uint_as_float(u);
}

union F4 { float4 v; float a[4]; };

__device__ __forceinline__ F4 f4max(F4 x, F4 y) {
    F4 r;
    r.a[0] = fmaxf(x.a[0], y.a[0]);
    r.a[1] = fmaxf(x.a[1], y.a[1]);
    r.a[2] = fmaxf(x.a[2], y.a[2]);
    r.a[3] = fmaxf(x.a[3], y.a[3]);
    return r;
}
__device__ __forceinline__ F4 f4neg() {
    F4 r;
    r.a[0] = r.a[1] = r.a[2] = r.a[3] = -INFINITY;
    return r;
}

// Hot loop: pure coalesced stream + vertical 3-max only (no halo, no cross-lane,
// no barriers). Horizontal check deferred to a rare path (~0.06% of elements)
// that does 6 scalar loads against L1-hot lines.
__global__ __launch_bounds__(BLK) void stage1_kernel(const float* __restrict__ y,
                                                     unsigned int* __restrict__ segcnt,
                                                     uint2* __restrict__ cand,
                                                     int segcap) {
    const int jb = blockIdx.x % JB;
    const int s  = (blockIdx.x / JB) % SPLITS;
    const int b  = blockIdx.x / (JB * SPLITS);
    const int t  = threadIdx.x;
    const int cg = t % 20;                 // channel quad (inner => coalesced)
    const int jl = t / 20;                 // 0..15
    const int j  = jb * JT + jl;
    const int i0 = s * RPT;
    const int seg = b * NSEG + s * JB + jb;
    const int iend = i0 + RPT;

    __shared__ unsigned int scount;
    if (t == 0) scount = 0u;
    __syncthreads();

    const float* __restrict__ yb  = y + (size_t)b * H * W * CP4;
    const float* __restrict__ col = yb + (size_t)j * CP4 + cg * 4;
    uint2* __restrict__ myseg = cand + (size_t)seg * segcap;

    auto ld = [&](int i) -> F4 {
        F4 v;
        if (i >= 0 && i < H) v.v = *(const float4*)(col + (size_t)i * W * CP4);
        else                 v = f4neg();
        return v;
    };

    // depth-2 pipeline: rows i-1, i, i+1 resident; i+2 in flight
    F4 v_p = ld(i0 - 1);
    F4 v_c = ld(i0);
    F4 v_n = ld(i0 + 1);

    for (int i = i0; i < iend; ++i) {
        const int inx = i + 2;
        F4 v_d;
        if (inx <= iend && inx < H) v_d = ld(inx);
        else                        v_d = f4neg();

        const F4 m = f4max(f4max(v_p, v_c), v_n);
        #pragma unroll
        for (int q = 0; q < 4; ++q) {
            const float cv = v_c.a[q];
            if (cv > THRESH && cv == m.a[q]) {
                // rare path: full 3x3 confirm via 6 scalar loads (side columns)
                const int c = cg * 4 + q;
                bool ok = true;
                #pragma unroll
                for (int di = -1; di <= 1; ++di) {
                    const int ii = i + di;
                    if (ii < 0 || ii >= H) continue;
                    const float* __restrict__ rr = yb + ((size_t)ii * W) * CP4 + c;
                    if (j > 0     && rr[(size_t)(j - 1) * CP4] > cv) ok = false;
                    if (j < W - 1 && rr[(size_t)(j + 1) * CP4] > cv) ok = false;
                }
                if (ok) {
                    const unsigned int p = atomicAdd(&scount, 1u);
                    if (p < (unsigned int)segcap) {
                        const unsigned int idx = (unsigned int)((i * W + j) * C + c);
                        myseg[p] = make_uint2(f2key(cv), idx);
                    }
                }
            }
        }
        v_p = v_c; v_c = v_n; v_n = v_d;
    }

    __syncthreads();
    if (t == 0) segcnt[seg] = min(scount, (unsigned int)segcap);
}

// One block per batch: radix-histogram select of top-K among candidates,
// exact stable rank of the survivors, compute final outputs.
__global__ __launch_bounds__(256) void stage2_kernel(const float* __restrict__ y,
                                                     const unsigned int* __restrict__ segcnt,
                                                     const uint2* __restrict__ cand,
                                                     int segcap,
                                                     float* __restrict__ out) {
    const int b = blockIdx.x;
    const int t = threadIdx.x;

    __shared__ unsigned int hist[NBINS];
    __shared__ uint2 coll[COLLECT_CAP];
    __shared__ unsigned int csum[256];
    __shared__ unsigned int scnt[NSEG];
    __shared__ unsigned int sT, sM;

    if (t < NSEG) scnt[t] = min(segcnt[b * NSEG + t], (unsigned int)segcap);
    for (int q = t; q < NBINS; q += 256) hist[q] = 0u;
    if (t == 0) sM = 0u;
    __syncthreads();

    for (int sg = 0; sg < NSEG; ++sg) {
        const uint2* __restrict__ cb = cand + (size_t)(b * NSEG + sg) * segcap;
        const unsigned int n = scnt[sg];
        for (unsigned int q = t; q < n; q += 256u)
            atomicAdd(&hist[cb[q].x >> 20], 1u);
    }
    __syncthreads();

    unsigned int sacc = 0;
    #pragma unroll
    for (int q = 0; q < 16; ++q) sacc += hist[t * 16 + q];
    csum[t] = sacc;
    __syncthreads();

    if (t == 0) {
        unsigned int cum = 0;
        int T = 0;
        bool found = false;
        for (int ch = 255; ch >= 0 && !found; --ch) {
            if (cum + csum[ch] >= (unsigned int)TOPK) {
                for (int bin = ch * 16 + 15; bin >= ch * 16; --bin) {
                    cum += hist[bin];
                    if (cum >= (unsigned int)TOPK) { T = bin; found = true; break; }
                }
            } else {
                cum += csum[ch];
            }
        }
        sT = found ? (unsigned int)T : 0u;
    }
    __syncthreads();

    const unsigned int T = sT;
    for (int sg = 0; sg < NSEG; ++sg) {
        const uint2* __restrict__ cb = cand + (size_t)(b * NSEG + sg) * segcap;
        const unsigned int n = scnt[sg];
        for (unsigned int q = t; q < n; q += 256u) {
            const uint2 e = cb[q];
            if ((e.x >> 20) >= T) {
                const unsigned int p = atomicAdd(&sM, 1u);
                if (p < (unsigned int)COLLECT_CAP) coll[p] = e;
            }
        }
    }
    __syncthreads();

    const unsigned int M = min(sM, (unsigned int)COLLECT_CAP);

    // exact stable rank: score desc, index asc (matches stable argsort(-score))
    for (unsigned int q = t; q < M; q += 256u) {
        const uint2 e = coll[q];
        unsigned int r = 0;
        for (unsigned int jx = 0; jx < M; ++jx) {
            const uint2 o = coll[jx];
            r += (o.x > e.x) || (o.x == e.x && o.y < e.y);
        }
        if (r < (unsigned int)TOPK) {
            const float score = key2f(e.x);
            const unsigned int idx = e.y;
            const unsigned int c  = idx % C;
            const unsigned int j2 = (idx / C) % W;
            const unsigned int i2 = idx / (C * W);
            const float* __restrict__ p = y + ((size_t)(b * H + i2) * W + j2) * CP4;
            const float w0 = expf(p[C + 0]) - 1.0f;
            const float w1 = expf(p[C + 1]) - 1.0f;
            const float b0 = p[C + 2];
            const float b1 = p[C + 3];
            const int o1 = b * TOPK + r;
            out[o1] = score;                                              // score_k
            out[BATCH * TOPK + o1] = (float)c;                            // k
            out[2 * BATCH * TOPK + 2 * o1 + 0] = 4.0f * (float)j2 + b0;   // centers x
            out[2 * BATCH * TOPK + 2 * o1 + 1] = 4.0f * (float)i2 + b1;   // centers y
            out[4 * BATCH * TOPK + 2 * o1 + 0] = 4.0f * w0;               // wh x
            out[4 * BATCH * TOPK + 2 * o1 + 1] = 4.0f * w1;               // wh y
        }
    }

    for (unsigned int q = M + t; q < (unsigned int)TOPK; q += 256u) {
        const int o1 = b * TOPK + q;
        out[o1] = 0.0f;
        out[BATCH * TOPK + o1] = 0.0f;
        out[2 * BATCH * TOPK + 2 * o1 + 0] = 0.0f;
        out[2 * BATCH * TOPK + 2 * o1 + 1] = 0.0f;
        out[4 * BATCH * TOPK + 2 * o1 + 0] = 0.0f;
        out[4 * BATCH * TOPK + 2 * o1 + 1] = 0.0f;
    }
}

extern "C" void kernel_launch(void* const* d_in, const int* in_sizes, int n_in,
                              void* d_out, int out_size, void* d_ws, size_t ws_size,
                              hipStream_t stream) {
    const float* y = (const float*)d_in[0];
    float* out = (float*)d_out;

    unsigned int* segcnt = (unsigned int*)d_ws;              // BATCH*NSEG counts
    uint2* cand = (uint2*)((char*)d_ws + 8192);

    int segcap = SEGCAP;
    const size_t avail = ws_size > 8192 ? ws_size - 8192 : 0;
    const size_t maxseg = avail / ((size_t)BATCH * NSEG * sizeof(uint2));
    if (maxseg < (size_t)segcap) segcap = (int)maxseg;

    stage1_kernel<<<BATCH * SPLITS * JB, BLK, 0, stream>>>(y, segcnt, cand, segcap);
    stage2_kernel<<<BATCH, 256, 0, stream>>>(y, segcnt, cand, segcap, out);
}

// Round 7
// 269.936 us; speedup vs baseline: 1.0712x; 1.0712x over previous
//
#include <hip/hip_runtime.h>
#include <math.h>

#define BATCH 64
#define H 80
#define W 80
#define C 80
#define CP4 84
#define TOPK 100
#define THRESH 2.5f
#define NBINS 4096
#define COLLECT_CAP 2048
#define SPLITS 4
#define RPT (H / SPLITS)       // 20 rows per block
#define CH 5                   // rows per load-chunk (MLP = 5)
#define JT 16                  // owned j-pixels per block
#define JB (W / JT)            // 5 j-tiles
#define NSEG (SPLITS * JB)     // 20 candidate segments per batch
#define SEGCAP 1024
#define BLK 320                // 5 waves; cg inner => contiguous 320B runs per j

// float -> monotonic sortable uint (ascending key == ascending float)
__device__ __forceinline__ unsigned int f2key(float f) {
    unsigned int u = __float_as_uint(f);
    return (u & 0x80000000u) ? ~u : (u | 0x80000000u);
}
__device__ __forceinline__ float key2f(unsigned int k) {
    unsigned int u = (k & 0x80000000u) ? (k & 0x7FFFFFFFu) : ~k;
    return __uint_as_float(u);
}

union F4 { float4 v; float a[4]; };

__device__ __forceinline__ F4 f4max(F4 x, F4 y) {
    F4 r;
    r.a[0] = fmaxf(x.a[0], y.a[0]);
    r.a[1] = fmaxf(x.a[1], y.a[1]);
    r.a[2] = fmaxf(x.a[2], y.a[2]);
    r.a[3] = fmaxf(x.a[3], y.a[3]);
    return r;
}
__device__ __forceinline__ F4 f4neg() {
    F4 r;
    r.a[0] = r.a[1] = r.a[2] = r.a[3] = -INFINITY;
    return r;
}

// Hot loop: coalesced stream, vertical 3-max only, CH independent loads in
// flight per thread (latency-bound fix). Horizontal check deferred to a rare
// path (~0.06% of elements) doing 6 scalar loads against hot lines.
__global__ __launch_bounds__(BLK) void stage1_kernel(const float* __restrict__ y,
                                                     unsigned int* __restrict__ segcnt,
                                                     uint2* __restrict__ cand,
                                                     int segcap) {
    const int jb = blockIdx.x % JB;
    const int s  = (blockIdx.x / JB) % SPLITS;
    const int b  = blockIdx.x / (JB * SPLITS);
    const int t  = threadIdx.x;
    const int cg = t % 20;                 // channel quad (inner => coalesced)
    const int jl = t / 20;                 // 0..15
    const int j  = jb * JT + jl;
    const int i0 = s * RPT;
    const int seg = b * NSEG + s * JB + jb;

    __shared__ unsigned int scount;
    if (t == 0) scount = 0u;
    __syncthreads();

    const float* __restrict__ yb  = y + (size_t)b * H * W * CP4;
    const float* __restrict__ col = yb + (size_t)j * CP4 + cg * 4;
    uint2* __restrict__ myseg = cand + (size_t)seg * segcap;

    auto ld = [&](int i) -> F4 {
        F4 v;
        if (i >= 0 && i < H) v.v = *(const float4*)(col + (size_t)i * W * CP4);
        else                 v = f4neg();
        return v;
    };

    F4 r0 = ld(i0 - 1);
    F4 r1 = ld(i0);

    #pragma unroll
    for (int cb = 0; cb < RPT; cb += CH) {
        F4 nw[CH];
        // CH independent loads issued back-to-back (progressive vmcnt drain)
        #pragma unroll
        for (int k = 0; k < CH; ++k) nw[k] = ld(i0 + cb + 1 + k);

        #pragma unroll
        for (int k = 0; k < CH; ++k) {
            const int i = i0 + cb + k;
            const F4 vp = (k == 0) ? r0 : (k == 1 ? r1 : nw[k - 2]);
            const F4 vc = (k == 0) ? r1 : nw[k - 1];
            const F4 vn = nw[k];
            const F4 m = f4max(f4max(vp, vc), vn);
            #pragma unroll
            for (int q = 0; q < 4; ++q) {
                const float cv = vc.a[q];
                if (cv > THRESH && cv == m.a[q]) {
                    // rare path: full 3x3 confirm via 6 scalar loads (side columns)
                    const int c = cg * 4 + q;
                    bool ok = true;
                    #pragma unroll
                    for (int di = -1; di <= 1; ++di) {
                        const int ii = i + di;
                        if (ii < 0 || ii >= H) continue;
                        const float* __restrict__ rr = yb + ((size_t)ii * W) * CP4 + c;
                        if (j > 0     && rr[(size_t)(j - 1) * CP4] > cv) ok = false;
                        if (j < W - 1 && rr[(size_t)(j + 1) * CP4] > cv) ok = false;
                    }
                    if (ok) {
                        const unsigned int p = atomicAdd(&scount, 1u);
                        if (p < (unsigned int)segcap) {
                            const unsigned int idx = (unsigned int)((i * W + j) * C + c);
                            myseg[p] = make_uint2(f2key(cv), idx);
                        }
                    }
                }
            }
        }
        r0 = nw[CH - 2];
        r1 = nw[CH - 1];
    }

    __syncthreads();
    if (t == 0) segcnt[seg] = min(scount, (unsigned int)segcap);
}

// One block per batch: radix-histogram select of top-K among candidates,
// exact stable rank of the survivors, compute final outputs.
__global__ __launch_bounds__(256) void stage2_kernel(const float* __restrict__ y,
                                                     const unsigned int* __restrict__ segcnt,
                                                     const uint2* __restrict__ cand,
                                                     int segcap,
                                                     float* __restrict__ out) {
    const int b = blockIdx.x;
    const int t = threadIdx.x;

    __shared__ unsigned int hist[NBINS];
    __shared__ uint2 coll[COLLECT_CAP];
    __shared__ unsigned int csum[256];
    __shared__ unsigned int scnt[NSEG];
    __shared__ unsigned int sT, sM;

    if (t < NSEG) scnt[t] = min(segcnt[b * NSEG + t], (unsigned int)segcap);
    for (int q = t; q < NBINS; q += 256) hist[q] = 0u;
    if (t == 0) sM = 0u;
    __syncthreads();

    for (int sg = 0; sg < NSEG; ++sg) {
        const uint2* __restrict__ cb = cand + (size_t)(b * NSEG + sg) * segcap;
        const unsigned int n = scnt[sg];
        for (unsigned int q = t; q < n; q += 256u)
            atomicAdd(&hist[cb[q].x >> 20], 1u);
    }
    __syncthreads();

    unsigned int sacc = 0;
    #pragma unroll
    for (int q = 0; q < 16; ++q) sacc += hist[t * 16 + q];
    csum[t] = sacc;
    __syncthreads();

    if (t == 0) {
        unsigned int cum = 0;
        int T = 0;
        bool found = false;
        for (int ch = 255; ch >= 0 && !found; --ch) {
            if (cum + csum[ch] >= (unsigned int)TOPK) {
                for (int bin = ch * 16 + 15; bin >= ch * 16; --bin) {
                    cum += hist[bin];
                    if (cum >= (unsigned int)TOPK) { T = bin; found = true; break; }
                }
            } else {
                cum += csum[ch];
            }
        }
        sT = found ? (unsigned int)T : 0u;
    }
    __syncthreads();

    const unsigned int T = sT;
    for (int sg = 0; sg < NSEG; ++sg) {
        const uint2* __restrict__ cb = cand + (size_t)(b * NSEG + sg) * segcap;
        const unsigned int n = scnt[sg];
        for (unsigned int q = t; q < n; q += 256u) {
            const uint2 e = cb[q];
            if ((e.x >> 20) >= T) {
                const unsigned int p = atomicAdd(&sM, 1u);
                if (p < (unsigned int)COLLECT_CAP) coll[p] = e;
            }
        }
    }
    __syncthreads();

    const unsigned int M = min(sM, (unsigned int)COLLECT_CAP);

    // exact stable rank: score desc, index asc (matches stable argsort(-score))
    for (unsigned int q = t; q < M; q += 256u) {
        const uint2 e = coll[q];
        unsigned int r = 0;
        for (unsigned int jx = 0; jx < M; ++jx) {
            const uint2 o = coll[jx];
            r += (o.x > e.x) || (o.x == e.x && o.y < e.y);
        }
        if (r < (unsigned int)TOPK) {
            const float score = key2f(e.x);
            const unsigned int idx = e.y;
            const unsigned int c  = idx % C;
            const unsigned int j2 = (idx / C) % W;
            const unsigned int i2 = idx / (C * W);
            const float* __restrict__ p = y + ((size_t)(b * H + i2) * W + j2) * CP4;
            const float w0 = expf(p[C + 0]) - 1.0f;
            const float w1 = expf(p[C + 1]) - 1.0f;
            const float b0 = p[C + 2];
            const float b1 = p[C + 3];
            const int o1 = b * TOPK + r;
            out[o1] = score;                                              // score_k
            out[BATCH * TOPK + o1] = (float)c;                            // k
            out[2 * BATCH * TOPK + 2 * o1 + 0] = 4.0f * (float)j2 + b0;   // centers x
            out[2 * BATCH * TOPK + 2 * o1 + 1] = 4.0f * (float)i2 + b1;   // centers y
            out[4 * BATCH * TOPK + 2 * o1 + 0] = 4.0f * w0;               // wh x
            out[4 * BATCH * TOPK + 2 * o1 + 1] = 4.0f * w1;               // wh y
        }
    }

    for (unsigned int q = M + t; q < (unsigned int)TOPK; q += 256u) {
        const int o1 = b * TOPK + q;
        out[o1] = 0.0f;
        out[BATCH * TOPK + o1] = 0.0f;
        out[2 * BATCH * TOPK + 2 * o1 + 0] = 0.0f;
        out[2 * BATCH * TOPK + 2 * o1 + 1] = 0.0f;
        out[4 * BATCH * TOPK + 2 * o1 + 0] = 0.0f;
        out[4 * BATCH * TOPK + 2 * o1 + 1] = 0.0f;
    }
}

extern "C" void kernel_launch(void* const* d_in, const int* in_sizes, int n_in,
                              void* d_out, int out_size, void* d_ws, size_t ws_size,
                              hipStream_t stream) {
    const float* y = (const float*)d_in[0];
    float* out = (float*)d_out;

    unsigned int* segcnt = (unsigned int*)d_ws;              // BATCH*NSEG counts
    uint2* cand = (uint2*)((char*)d_ws + 8192);

    int segcap = SEGCAP;
    const size_t avail = ws_size > 8192 ? ws_size - 8192 : 0;
    const size_t maxseg = avail / ((size_t)BATCH * NSEG * sizeof(uint2));
    if (maxseg < (size_t)segcap) segcap = (int)maxseg;

    stage1_kernel<<<BATCH * SPLITS * JB, BLK, 0, stream>>>(y, segcnt, cand, segcap);
    stage2_kernel<<<BATCH, 256, 0, stream>>>(y, segcnt, cand, segcap, out);
}